// Round 4
// baseline (7530.400 us; speedup 1.0000x reference)
//
#include <hip/hip_runtime.h>
#include <hip/hip_bf16.h>

// Problem constants: B=64, T=2048, IN_F=128, H1=OUT_F=64, 4H=256
#define BB 64
#define TT 2048
#define INF 128
#define HH 64
#define GG 256  // 4*H

__device__ __forceinline__ float sigm(float x) { return 1.0f / (1.0f + __expf(-x)); }
__device__ __forceinline__ float tanh_f(float x) {
  float e = __expf(2.0f * x);
  return 1.0f - 2.0f / (e + 1.0f);
}
// Wave-uniform broadcast of lane l's value via v_readlane (SGPR path, no LDS).
__device__ __forceinline__ float bcast(float v, int l) {
  return __uint_as_float(__builtin_amdgcn_readlane(__float_as_uint(v), l));
}

// ---------------------------------------------------------------------------
// Round-3 post-mortem: sync is NOT the bottleneck (r0 uncached == r3 cached).
// The recurrence wave's 256-float weight set cannot be arch-VGPR-resident
// (VGPR_Count pinned at 144) -> AGPR spill, v_accvgpr_read per use + hazard
// stalls ~= the measured 2480cy step. Round 4: STREAM the recurrent weights
// from L2 every step (64KB, permanently hot) instead of holding them:
//   per 4-k group: 4x global_load_dwordx4 (L2 ~200cy, hidden by fma lookahead)
// Guards: (a) inline-asm-laundered offset defeats LICM (else the compiler
// re-hoists the loads into registers and recreates the spill); (b)
// sched_barrier(0) every 4 groups caps in-flight loads (~16 float4) so the
// scheduler can't blow register pressure by batching all 64 loads.
// ---------------------------------------------------------------------------

// Streamed 4-k group: loads then 4 broadcasts + 16 fma.
#define SG1(G) {                                                              \
    const float4 vi = wI[(G)]; const float4 vf = wF[(G)];                     \
    const float4 vg = wGp[(G)]; const float4 vo = wO[(G)];                    \
    const float k0 = bcast(hv, 4*(G)+0), k1 = bcast(hv, 4*(G)+1),             \
                k2 = bcast(hv, 4*(G)+2), k3 = bcast(hv, 4*(G)+3);             \
    ai = fmaf(k0, vi.x, ai); af = fmaf(k0, vf.x, af);                         \
    ag = fmaf(k0, vg.x, ag); ao = fmaf(k0, vo.x, ao);                         \
    ai = fmaf(k1, vi.y, ai); af = fmaf(k1, vf.y, af);                         \
    ag = fmaf(k1, vg.y, ag); ao = fmaf(k1, vo.y, ao);                         \
    ai = fmaf(k2, vi.z, ai); af = fmaf(k2, vf.z, af);                         \
    ag = fmaf(k2, vg.z, ag); ao = fmaf(k2, vo.z, ao);                         \
    ai = fmaf(k3, vi.w, ai); af = fmaf(k3, vf.w, af);                         \
    ag = fmaf(k3, vg.w, ag); ao = fmaf(k3, vo.w, ao); }
#define SGB __builtin_amdgcn_sched_barrier(0);
#define SDOT16 SG1(0) SG1(1) SG1(2) SG1(3) SGB                                \
               SG1(4) SG1(5) SG1(6) SG1(7) SGB                                \
               SG1(8) SG1(9) SG1(10) SG1(11) SGB                              \
               SG1(12) SG1(13) SG1(14) SG1(15)

// X-wave (feed-forward) register-resident scheme, unchanged from round 3.
#define WL1(I)                                                                  \
  { float4 a = p[lane * 16 + (I)];                                              \
    wi[4*(I)] = a.x; wi[4*(I)+1] = a.y; wi[4*(I)+2] = a.z; wi[4*(I)+3] = a.w;   \
    float4 c = p[(64 + lane) * 16 + (I)];                                       \
    wf[4*(I)] = c.x; wf[4*(I)+1] = c.y; wf[4*(I)+2] = c.z; wf[4*(I)+3] = c.w;   \
    float4 d = p[(128 + lane) * 16 + (I)];                                      \
    wg[4*(I)] = d.x; wg[4*(I)+1] = d.y; wg[4*(I)+2] = d.z; wg[4*(I)+3] = d.w;   \
    float4 e = p[(192 + lane) * 16 + (I)];                                      \
    wo[4*(I)] = e.x; wo[4*(I)+1] = e.y; wo[4*(I)+2] = e.z; wo[4*(I)+3] = e.w; }
#define WL4(I) WL1(I) WL1((I)+1) WL1((I)+2) WL1((I)+3)
#define WLOAD WL4(0) WL4(4) WL4(8) WL4(12)

#define D1(K)                                              \
  { float hk = bcast(hv, (K));                             \
    ai = fmaf(hk, wi[(K)], ai); af = fmaf(hk, wf[(K)], af);\
    ag = fmaf(hk, wg[(K)], ag); ao = fmaf(hk, wo[(K)], ao); }
#define D8(K) D1(K) D1((K)+1) D1((K)+2) D1((K)+3) D1((K)+4) D1((K)+5) D1((K)+6) D1((K)+7)
#define DOT64 D8(0) D8(8) D8(16) D8(24) D8(32) D8(40) D8(48) D8(56)

// ---------------------------------------------------------------------------
// Kernel 1: xg1[m][n] = X[m,:].W_ih1[n,:] + b_ih1[n] + b_hh1[n]  (unchanged)
// ---------------------------------------------------------------------------
#define YW1(I) { float4 a_ = Wp[t * 32 + (I)];                                   \
    wr[4*(I)] = a_.x; wr[4*(I)+1] = a_.y; wr[4*(I)+2] = a_.z; wr[4*(I)+3] = a_.w; }
#define YW4(I) YW1(I) YW1((I)+1) YW1((I)+2) YW1((I)+3)
#define YWLOAD YW4(0) YW4(4) YW4(8) YW4(12) YW4(16) YW4(20) YW4(24) YW4(28)

#define YD1(L)                                                   \
  { float xa = bcast(curx, (L)); float xb = bcast(cury, (L));    \
    ae = fmaf(xa, wr[2*(L)], ae); ao = fmaf(xb, wr[2*(L)+1], ao); }
#define YD8(L) YD1(L) YD1((L)+1) YD1((L)+2) YD1((L)+3) YD1((L)+4) YD1((L)+5) YD1((L)+6) YD1((L)+7)
#define YDOT64 YD8(0) YD8(8) YD8(16) YD8(24) YD8(32) YD8(40) YD8(48) YD8(56)

__global__ __launch_bounds__(256, 1) void xgemm(const float* __restrict__ X,
                                                const float* __restrict__ W,
                                                const float* __restrict__ bi,
                                                const float* __restrict__ bh,
                                                float* __restrict__ XG) {
  const int t = threadIdx.x;            // 0..255 = owned W row
  const int lane = t & 63;
  const long m0 = (long)blockIdx.x * 256;

  float wr[INF];
  const float4* Wp = (const float4*)W;
  YWLOAD
  const float bias = bi[t] + bh[t];

  const float2* Xp = (const float2*)X;  // lane l holds k=2l,2l+1
  float2 cur = Xp[(size_t)m0 * 64 + lane];
  float2 nx1 = Xp[(size_t)(m0 + 1) * 64 + lane];

  for (int mi = 0; mi < 256; ++mi) {
    const long m = m0 + mi;
    float2 nx2 = make_float2(0.f, 0.f);
    if (mi + 2 < 256) nx2 = Xp[(size_t)(m + 2) * 64 + lane];

    const float curx = cur.x, cury = cur.y;
    float ae = bias, ao = 0.f;
    YDOT64
    XG[(size_t)m * GG + t] = ae + ao;
    cur = nx1; nx1 = nx2;
  }
}

// ---------------------------------------------------------------------------
// Kernel 2: 4-wave pipeline, one wave per SIMD.
//  wid 0: W0  L1 recurrence, STREAMED Whh1      -> x2 ring     (SIMD0)
//  wid 1: Xe  Wih2 dot (reg-resident), even s   -> a2x ring    (SIMD1)
//  wid 2: Xo  Wih2 dot (reg-resident), odd  s   -> a2x ring    (SIMD2)
//  wid 3: W2  L2 recurrence, STREAMED Whh2, a2x read pre-dot   (SIMD3)
// ---------------------------------------------------------------------------
__global__ __launch_bounds__(256, 1)
void lstm2(const float* __restrict__ XG,
           const float* __restrict__ Whh1,
           const float* __restrict__ Wih2,
           const float* __restrict__ Whh2,
           const float* __restrict__ bi2,
           const float* __restrict__ bh2,
           const float* __restrict__ m1g,
           const float* __restrict__ m2g,
           float* __restrict__ out) {
  const int b = blockIdx.x;
  const int wid = threadIdx.x >> 6;
  const int lane = threadIdx.x & 63;

  __shared__ int f_h1, f_xe, f_xo, f_2;             // monotonic step counters
  __shared__ __align__(16) float x2buf[8][HH];      // W0 -> Xe/Xo ring
  __shared__ __align__(16) float a2xbuf[8][GG];     // Xe/Xo -> W2 ring

  if (threadIdx.x == 0) { f_h1 = 0; f_xe = 0; f_xo = 0; f_2 = 0; }
  __syncthreads();  // one-time

// Cached wait: touch LDS only when cached value insufficient (flags monotonic).
#define WAITC(seen, flag, tgt)                                  \
  do {                                                          \
    if ((seen) < (tgt)) {                                       \
      while (((seen) = *(volatile int*)&(flag)) < (tgt)) {}     \
    }                                                           \
    asm volatile("" ::: "memory");                              \
  } while (0)
#define PUBLISH(flag, val)                                      \
  do {                                                          \
    asm volatile("s_waitcnt lgkmcnt(0)" ::: "memory");          \
    if (lane == 0) *(volatile int*)&(flag) = (val);             \
  } while (0)

  if (wid == 0) {
    // ---- W0: layer-1 recurrence, weights streamed from L2 ----
    const float m1 = m1g[b * HH + lane];
    const float* xgp = XG + (size_t)b * TT * GG;
    const float4* Wb = (const float4*)Whh1;

    float cur0 = xgp[lane], cur1 = xgp[64 + lane], cur2 = xgp[128 + lane], cur3 = xgp[192 + lane];
    float n10 = xgp[GG + lane], n11 = xgp[GG + 64 + lane], n12 = xgp[GG + 128 + lane], n13 = xgp[GG + 192 + lane];

    float h1 = 0.f, c1 = 0.f;
    int sxe = 0, sxo = 0;
    for (int s = 0; s < TT; ++s) {
      // Launder a zero offset so the 64 weight loads are NOT loop-invariant
      // (else LICM re-hoists them into registers -> AGPR spill returns).
      unsigned woff = 0u;
      asm volatile("" : "+v"(woff));
      const float4* wI  = Wb + (size_t)lane * 16 + woff;
      const float4* wF  = Wb + (size_t)(64 + lane) * 16 + woff;
      const float4* wGp = Wb + (size_t)(128 + lane) * 16 + woff;
      const float4* wO  = Wb + (size_t)(192 + lane) * 16 + woff;

      float n20 = 0.f, n21 = 0.f, n22 = 0.f, n23 = 0.f;
      if (s + 2 < TT) {
        const float* q = xgp + (size_t)(s + 2) * GG;
        n20 = q[lane]; n21 = q[64 + lane]; n22 = q[128 + lane]; n23 = q[192 + lane];
      }

      const float hv = h1;
      float ai = cur0, af = cur1, ag = cur2, ao = cur3;
      SDOT16
      c1 = sigm(af) * c1 + sigm(ai) * tanh_f(ag);
      h1 = sigm(ao) * tanh_f(c1);

      if (s & 1) { WAITC(sxo, f_xo, s - 7); }
      else       { WAITC(sxe, f_xe, s - 7); }
      x2buf[s & 7][lane] = h1 * m1;
      PUBLISH(f_h1, s + 1);

      cur0 = n10; cur1 = n11; cur2 = n12; cur3 = n13;
      n10 = n20; n11 = n21; n12 = n22; n13 = n23;
    }
  } else if (wid == 3) {
    // ---- W2: layer-2 recurrence, weights streamed from L2 ----
    const float m2v = m2g[b * HH + lane];
    float* ob = out + (size_t)b * TT * HH;
    const float4* Wb = (const float4*)Whh2;

    float h2 = 0.f, c2 = 0.f;
    int sxe = 0, sxo = 0;
    for (int s = 0; s < TT; ++s) {
      unsigned woff = 0u;
      asm volatile("" : "+v"(woff));
      const float4* wI  = Wb + (size_t)lane * 16 + woff;
      const float4* wF  = Wb + (size_t)(64 + lane) * 16 + woff;
      const float4* wGp = Wb + (size_t)(128 + lane) * 16 + woff;
      const float4* wO  = Wb + (size_t)(192 + lane) * 16 + woff;

      if (s & 1) { WAITC(sxo, f_xo, s + 1); }
      else       { WAITC(sxe, f_xe, s + 1); }
      // issue the 4 ring reads NOW; latency hides under the dot
      const float pi = a2xbuf[s & 7][lane];
      const float pf = a2xbuf[s & 7][64 + lane];
      const float pg = a2xbuf[s & 7][128 + lane];
      const float po = a2xbuf[s & 7][192 + lane];

      const float hv = h2;
      float ai = 0.f, af = 0.f, ag = 0.f, ao = 0.f;
      SDOT16
      ai += pi; af += pf; ag += pg; ao += po;

      c2 = sigm(af) * c2 + sigm(ai) * tanh_f(ag);
      h2 = sigm(ao) * tanh_f(c2);
      PUBLISH(f_2, s + 1);    // lgkmcnt(0) drains a2x reads -> slot consumed
      ob[(size_t)s * HH + lane] = fmaxf(h2 * m2v, 0.f);
    }
  } else {
    // ---- Xe (wid 1) / Xo (wid 2): Wih2 dot, parity-split, reg-resident ----
    float wi[HH], wf[HH], wg[HH], wo[HH];
    const float4* p = (const float4*)Wih2;
    WLOAD
    const float bi_i = bi2[lane] + bh2[lane];
    const float bi_f = bi2[64 + lane] + bh2[64 + lane];
    const float bi_g = bi2[128 + lane] + bh2[128 + lane];
    const float bi_o = bi2[192 + lane] + bh2[192 + lane];

    const int par = wid - 1;                       // 0 = even steps, 1 = odd
    volatile int* const myflag = par ? (volatile int*)&f_xo : (volatile int*)&f_xe;
    int s0 = 0, s2 = 0;
    for (int s = par; s < TT; s += 2) {
      WAITC(s0, f_h1, s + 1);
      const float hv = x2buf[s & 7][lane];

      float ai = bi_i, af = bi_f, ag = bi_g, ao = bi_o;
      DOT64

      WAITC(s2, f_2, s - 7);   // a2x slot (s&7) free? prev occupant s-8.
      a2xbuf[s & 7][lane] = ai;
      a2xbuf[s & 7][64 + lane] = af;
      a2xbuf[s & 7][128 + lane] = ag;
      a2xbuf[s & 7][192 + lane] = ao;
      PUBLISH(*myflag, s + 1);
    }
  }
#undef WAITC
#undef PUBLISH
}

extern "C" void kernel_launch(void* const* d_in, const int* in_sizes, int n_in,
                              void* d_out, int out_size, void* d_ws, size_t ws_size,
                              hipStream_t stream) {
  (void)in_sizes; (void)n_in; (void)out_size; (void)ws_size;
  const float* x     = (const float*)d_in[0];
  const float* W_ih1 = (const float*)d_in[1];
  const float* W_hh1 = (const float*)d_in[2];
  const float* b_ih1 = (const float*)d_in[3];
  const float* b_hh1 = (const float*)d_in[4];
  const float* W_ih2 = (const float*)d_in[5];
  const float* W_hh2 = (const float*)d_in[6];
  const float* b_ih2 = (const float*)d_in[7];
  const float* b_hh2 = (const float*)d_in[8];
  const float* mask1 = (const float*)d_in[9];
  const float* mask2 = (const float*)d_in[10];
  float* out = (float*)d_out;

  float* xg1 = (float*)d_ws;  // B*T*4H fp32 = 134,217,728 bytes

  xgemm<<<dim3(BB * TT / 256), dim3(256), 0, stream>>>(x, W_ih1, b_ih1, b_hh1, xg1);
  lstm2<<<dim3(BB), dim3(256), 0, stream>>>(xg1, W_hh1, W_ih2, W_hh2, b_ih2, b_hh2,
                                            mask1, mask2, out);
}

// Round 5
// 4138.111 us; speedup vs baseline: 1.8198x; 1.8198x over previous
//
#include <hip/hip_runtime.h>
#include <hip/hip_bf16.h>

// Problem constants: B=64, T=2048, IN_F=128, H1=OUT_F=64, 4H=256
#define BB 64
#define TT 2048
#define INF 128
#define HH 64
#define GG 256  // 4*H

__device__ __forceinline__ float sigm(float x) { return 1.0f / (1.0f + __expf(-x)); }
__device__ __forceinline__ float tanh_f(float x) {
  float e = __expf(2.0f * x);
  return 1.0f - 2.0f / (e + 1.0f);
}
// Wave-uniform broadcast of lane l's value via v_readlane (SGPR path, no LDS).
__device__ __forceinline__ float bcast(float v, int l) {
  return __uint_as_float(__builtin_amdgcn_readlane(__float_as_uint(v), l));
}

// ---------------------------------------------------------------------------
// Round-4 post-mortem: streaming weights from L2 inside the recurrence is
// latency-poisoned (VALUBusy 4%, 3.4x regression). Round-3 post-mortem:
// register-resident weights are issue-poisoned (~2200cy issue/step: 256
// weights + state > 256 arch VGPRs -> ACC-file residency, accvgpr_read per
// use). Round 5: weights live in LDS, TRANSPOSED, re-read every step.
//   PA[k][l] = (W[l][k], W[64+l][k]); PB[k][l] = (W[128+l][k], W[192+l][k])
//   -> per k: 2x ds_read_b64 (structurally conflict-free: 128 dwords over
//      32 banks = exact 2-way) + 1 readlane + 4 fma.
// 2-deep double-buffered (4 k's per group) so ~120cy LDS latency hides.
// ~1000cy issue/step, zero AGPR traffic. One-time cooperative transpose of
// Whh1+Whh2 into 128KB dynamic LDS. X-waves keep reg/AGPR weights (2x slack
// absorbs the tax). Sync fabric = round-3's (validated, null-cost).
// Per-gate k-accumulation order unchanged -> bit-identical numerics.
// ---------------------------------------------------------------------------

// ---- LDS-dot macros (named double buffers X/Y, literal indices only) ----
#define LSD_LD(S, K)                                   \
  pa##S##0 = PAp[((K)+0)*64 + lane];                   \
  pb##S##0 = PBp[((K)+0)*64 + lane];                   \
  pa##S##1 = PAp[((K)+1)*64 + lane];                   \
  pb##S##1 = PBp[((K)+1)*64 + lane];                   \
  pa##S##2 = PAp[((K)+2)*64 + lane];                   \
  pb##S##2 = PBp[((K)+2)*64 + lane];                   \
  pa##S##3 = PAp[((K)+3)*64 + lane];                   \
  pb##S##3 = PBp[((K)+3)*64 + lane];

#define LSD_FM1(PA_, PB_, KK)                          \
  { const float kk_ = bcast(hv, (KK));                 \
    ai = fmaf(kk_, PA_.x, ai); af = fmaf(kk_, PA_.y, af); \
    ag = fmaf(kk_, PB_.x, ag); ao = fmaf(kk_, PB_.y, ao); }

#define LSD_FM(S, K)                                   \
  LSD_FM1(pa##S##0, pb##S##0, (K)+0)                   \
  LSD_FM1(pa##S##1, pb##S##1, (K)+1)                   \
  LSD_FM1(pa##S##2, pb##S##2, (K)+2)                   \
  LSD_FM1(pa##S##3, pb##S##3, (K)+3)

// Software-pipelined 64-k dot: load group g+2 while computing group g.
#define LDOT                                           \
  LSD_LD(X, 0) LSD_LD(Y, 4)                            \
  LSD_FM(X, 0)  LSD_LD(X, 8)  LSD_FM(Y, 4)  LSD_LD(Y, 12) \
  LSD_FM(X, 8)  LSD_LD(X, 16) LSD_FM(Y, 12) LSD_LD(Y, 20) \
  LSD_FM(X, 16) LSD_LD(X, 24) LSD_FM(Y, 20) LSD_LD(Y, 28) \
  LSD_FM(X, 24) LSD_LD(X, 32) LSD_FM(Y, 28) LSD_LD(Y, 36) \
  LSD_FM(X, 32) LSD_LD(X, 40) LSD_FM(Y, 36) LSD_LD(Y, 44) \
  LSD_FM(X, 40) LSD_LD(X, 48) LSD_FM(Y, 44) LSD_LD(Y, 52) \
  LSD_FM(X, 48) LSD_LD(X, 56) LSD_FM(Y, 52) LSD_LD(Y, 60) \
  LSD_FM(X, 56) LSD_FM(Y, 60)

#define LSD_DECL                                                   \
  float2 paX0, paX1, paX2, paX3, pbX0, pbX1, pbX2, pbX3;           \
  float2 paY0, paY1, paY2, paY3, pbY0, pbY1, pbY2, pbY3;

// ---- X-wave (feed-forward) register-resident scheme, unchanged ----
#define WL1(I)                                                                  \
  { float4 a = p[lane * 16 + (I)];                                              \
    wi[4*(I)] = a.x; wi[4*(I)+1] = a.y; wi[4*(I)+2] = a.z; wi[4*(I)+3] = a.w;   \
    float4 c = p[(64 + lane) * 16 + (I)];                                       \
    wf[4*(I)] = c.x; wf[4*(I)+1] = c.y; wf[4*(I)+2] = c.z; wf[4*(I)+3] = c.w;   \
    float4 d = p[(128 + lane) * 16 + (I)];                                      \
    wg[4*(I)] = d.x; wg[4*(I)+1] = d.y; wg[4*(I)+2] = d.z; wg[4*(I)+3] = d.w;   \
    float4 e = p[(192 + lane) * 16 + (I)];                                      \
    wo[4*(I)] = e.x; wo[4*(I)+1] = e.y; wo[4*(I)+2] = e.z; wo[4*(I)+3] = e.w; }
#define WL4(I) WL1(I) WL1((I)+1) WL1((I)+2) WL1((I)+3)
#define WLOAD WL4(0) WL4(4) WL4(8) WL4(12)

#define D1(K)                                              \
  { float hk = bcast(hv, (K));                             \
    ai = fmaf(hk, wi[(K)], ai); af = fmaf(hk, wf[(K)], af);\
    ag = fmaf(hk, wg[(K)], ag); ao = fmaf(hk, wo[(K)], ao); }
#define D8(K) D1(K) D1((K)+1) D1((K)+2) D1((K)+3) D1((K)+4) D1((K)+5) D1((K)+6) D1((K)+7)
#define DOT64 D8(0) D8(8) D8(16) D8(24) D8(32) D8(40) D8(48) D8(56)

// ---------------------------------------------------------------------------
// Kernel 1: xg1[m][n] = X[m,:].W_ih1[n,:] + b_ih1[n] + b_hh1[n]  (unchanged)
// ---------------------------------------------------------------------------
#define YW1(I) { float4 a_ = Wp[t * 32 + (I)];                                   \
    wr[4*(I)] = a_.x; wr[4*(I)+1] = a_.y; wr[4*(I)+2] = a_.z; wr[4*(I)+3] = a_.w; }
#define YW4(I) YW1(I) YW1((I)+1) YW1((I)+2) YW1((I)+3)
#define YWLOAD YW4(0) YW4(4) YW4(8) YW4(12) YW4(16) YW4(20) YW4(24) YW4(28)

#define YD1(L)                                                   \
  { float xa = bcast(curx, (L)); float xb = bcast(cury, (L));    \
    ae = fmaf(xa, wr[2*(L)], ae); ao = fmaf(xb, wr[2*(L)+1], ao); }
#define YD8(L) YD1(L) YD1((L)+1) YD1((L)+2) YD1((L)+3) YD1((L)+4) YD1((L)+5) YD1((L)+6) YD1((L)+7)
#define YDOT64 YD8(0) YD8(8) YD8(16) YD8(24) YD8(32) YD8(40) YD8(48) YD8(56)

__global__ __launch_bounds__(256, 1) void xgemm(const float* __restrict__ X,
                                                const float* __restrict__ W,
                                                const float* __restrict__ bi,
                                                const float* __restrict__ bh,
                                                float* __restrict__ XG) {
  const int t = threadIdx.x;            // 0..255 = owned W row
  const int lane = t & 63;
  const long m0 = (long)blockIdx.x * 256;

  float wr[INF];
  const float4* Wp = (const float4*)W;
  YWLOAD
  const float bias = bi[t] + bh[t];

  const float2* Xp = (const float2*)X;  // lane l holds k=2l,2l+1
  float2 cur = Xp[(size_t)m0 * 64 + lane];
  float2 nx1 = Xp[(size_t)(m0 + 1) * 64 + lane];

  for (int mi = 0; mi < 256; ++mi) {
    const long m = m0 + mi;
    float2 nx2 = make_float2(0.f, 0.f);
    if (mi + 2 < 256) nx2 = Xp[(size_t)(m + 2) * 64 + lane];

    const float curx = cur.x, cury = cur.y;
    float ae = bias, ao = 0.f;
    YDOT64
    XG[(size_t)m * GG + t] = ae + ao;
    cur = nx1; nx1 = nx2;
  }
}

// ---------------------------------------------------------------------------
// Kernel 2: 4-wave pipeline, one wave per SIMD.
//  wid 0: W0  L1 recurrence, LDS-transposed Whh1  -> x2 ring   (SIMD0)
//  wid 1: Xe  Wih2 dot (reg/AGPR), even steps     -> a2x ring  (SIMD1)
//  wid 2: Xo  Wih2 dot (reg/AGPR), odd  steps     -> a2x ring  (SIMD2)
//  wid 3: W2  L2 recurrence, LDS-transposed Whh2, a2x pre-read (SIMD3)
// Dynamic LDS: PA1|PB1|PA2|PB2, each [64][64] float2 = 32KB (128KB total).
// ---------------------------------------------------------------------------
__global__ __launch_bounds__(256, 1)
void lstm2(const float* __restrict__ XG,
           const float* __restrict__ Whh1,
           const float* __restrict__ Wih2,
           const float* __restrict__ Whh2,
           const float* __restrict__ bi2,
           const float* __restrict__ bh2,
           const float* __restrict__ m1g,
           const float* __restrict__ m2g,
           float* __restrict__ out) {
  const int b = blockIdx.x;
  const int wid = threadIdx.x >> 6;
  const int lane = threadIdx.x & 63;

  extern __shared__ __align__(16) char dynls[];
  float2* const PA1 = (float2*)dynls;       // [64][64]: (Wi,Wf) pairs, k-major
  float2* const PB1 = PA1 + 64 * 64;        // (Wg,Wo)
  float2* const PA2 = PB1 + 64 * 64;
  float2* const PB2 = PA2 + 64 * 64;

  __shared__ int f_h1, f_xe, f_xo, f_2;             // monotonic step counters
  __shared__ __align__(16) float x2buf[8][HH];      // W0 -> Xe/Xo ring
  __shared__ __align__(16) float a2xbuf[8][GG];     // Xe/Xo -> W2 ring

  if (threadIdx.x == 0) { f_h1 = 0; f_xe = 0; f_xo = 0; f_2 = 0; }

  // One-time cooperative transpose: global (row-major [n][k]) -> LDS k-major
  // gate-pair float2. Reads coalesced (k fastest within a wave).
  for (int idx = threadIdx.x; idx < 64 * 64; idx += 256) {
    const int l = idx >> 6, k = idx & 63;
    PA1[(k << 6) | l] = make_float2(Whh1[l * 64 + k],         Whh1[(64 + l) * 64 + k]);
    PB1[(k << 6) | l] = make_float2(Whh1[(128 + l) * 64 + k], Whh1[(192 + l) * 64 + k]);
    PA2[(k << 6) | l] = make_float2(Whh2[l * 64 + k],         Whh2[(64 + l) * 64 + k]);
    PB2[(k << 6) | l] = make_float2(Whh2[(128 + l) * 64 + k], Whh2[(192 + l) * 64 + k]);
  }
  __syncthreads();  // one-time

// Cached wait: touch LDS only when cached value insufficient (flags monotonic).
#define WAITC(seen, flag, tgt)                                  \
  do {                                                          \
    if ((seen) < (tgt)) {                                       \
      while (((seen) = *(volatile int*)&(flag)) < (tgt)) {}     \
    }                                                           \
    asm volatile("" ::: "memory");                              \
  } while (0)
#define PUBLISH(flag, val)                                      \
  do {                                                          \
    asm volatile("s_waitcnt lgkmcnt(0)" ::: "memory");          \
    if (lane == 0) *(volatile int*)&(flag) = (val);             \
  } while (0)

  if (wid == 0) {
    // ---- W0: layer-1 recurrence, LDS-transposed Whh1 ----
    const float2* const PAp = PA1;
    const float2* const PBp = PB1;
    const float m1 = m1g[b * HH + lane];
    const float* xgp = XG + (size_t)b * TT * GG;

    float cur0 = xgp[lane], cur1 = xgp[64 + lane], cur2 = xgp[128 + lane], cur3 = xgp[192 + lane];
    float n10 = xgp[GG + lane], n11 = xgp[GG + 64 + lane], n12 = xgp[GG + 128 + lane], n13 = xgp[GG + 192 + lane];

    LSD_DECL
    float h1 = 0.f, c1 = 0.f;
    int sxe = 0, sxo = 0;
    for (int s = 0; s < TT; ++s) {
      float n20 = 0.f, n21 = 0.f, n22 = 0.f, n23 = 0.f;
      if (s + 2 < TT) {
        const float* q = xgp + (size_t)(s + 2) * GG;
        n20 = q[lane]; n21 = q[64 + lane]; n22 = q[128 + lane]; n23 = q[192 + lane];
      }

      const float hv = h1;
      float ai = cur0, af = cur1, ag = cur2, ao = cur3;
      LDOT
      c1 = sigm(af) * c1 + sigm(ai) * tanh_f(ag);
      h1 = sigm(ao) * tanh_f(c1);

      if (s & 1) { WAITC(sxo, f_xo, s - 7); }
      else       { WAITC(sxe, f_xe, s - 7); }
      x2buf[s & 7][lane] = h1 * m1;
      PUBLISH(f_h1, s + 1);

      cur0 = n10; cur1 = n11; cur2 = n12; cur3 = n13;
      n10 = n20; n11 = n21; n12 = n22; n13 = n23;
    }
  } else if (wid == 3) {
    // ---- W2: layer-2 recurrence, LDS-transposed Whh2 ----
    const float2* const PAp = PA2;
    const float2* const PBp = PB2;
    const float m2v = m2g[b * HH + lane];
    float* ob = out + (size_t)b * TT * HH;

    LSD_DECL
    float h2 = 0.f, c2 = 0.f;
    int sxe = 0, sxo = 0;
    for (int s = 0; s < TT; ++s) {
      if (s & 1) { WAITC(sxo, f_xo, s + 1); }
      else       { WAITC(sxe, f_xe, s + 1); }
      // issue the 4 ring reads NOW; latency hides under the dot
      const float pi = a2xbuf[s & 7][lane];
      const float pf = a2xbuf[s & 7][64 + lane];
      const float pg = a2xbuf[s & 7][128 + lane];
      const float po = a2xbuf[s & 7][192 + lane];

      const float hv = h2;
      float ai = 0.f, af = 0.f, ag = 0.f, ao = 0.f;
      LDOT
      ai += pi; af += pf; ag += pg; ao += po;

      c2 = sigm(af) * c2 + sigm(ai) * tanh_f(ag);
      h2 = sigm(ao) * tanh_f(c2);
      PUBLISH(f_2, s + 1);    // lgkmcnt(0) drains a2x reads -> slot consumed
      ob[(size_t)s * HH + lane] = fmaxf(h2 * m2v, 0.f);
    }
  } else {
    // ---- Xe (wid 1) / Xo (wid 2): Wih2 dot, parity-split, reg-resident ----
    float wi[HH], wf[HH], wg[HH], wo[HH];
    const float4* p = (const float4*)Wih2;
    WLOAD
    const float bi_i = bi2[lane] + bh2[lane];
    const float bi_f = bi2[64 + lane] + bh2[64 + lane];
    const float bi_g = bi2[128 + lane] + bh2[128 + lane];
    const float bi_o = bi2[192 + lane] + bh2[192 + lane];

    const int par = wid - 1;                       // 0 = even steps, 1 = odd
    volatile int* const myflag = par ? (volatile int*)&f_xo : (volatile int*)&f_xe;
    int s0 = 0, s2 = 0;
    for (int s = par; s < TT; s += 2) {
      WAITC(s0, f_h1, s + 1);
      const float hv = x2buf[s & 7][lane];

      float ai = bi_i, af = bi_f, ag = bi_g, ao = bi_o;
      DOT64

      WAITC(s2, f_2, s - 7);   // a2x slot (s&7) free? prev occupant s-8.
      a2xbuf[s & 7][lane] = ai;
      a2xbuf[s & 7][64 + lane] = af;
      a2xbuf[s & 7][128 + lane] = ag;
      a2xbuf[s & 7][192 + lane] = ao;
      PUBLISH(*myflag, s + 1);
    }
  }
#undef WAITC
#undef PUBLISH
}

extern "C" void kernel_launch(void* const* d_in, const int* in_sizes, int n_in,
                              void* d_out, int out_size, void* d_ws, size_t ws_size,
                              hipStream_t stream) {
  (void)in_sizes; (void)n_in; (void)out_size; (void)ws_size;
  const float* x     = (const float*)d_in[0];
  const float* W_ih1 = (const float*)d_in[1];
  const float* W_hh1 = (const float*)d_in[2];
  const float* b_ih1 = (const float*)d_in[3];
  const float* b_hh1 = (const float*)d_in[4];
  const float* W_ih2 = (const float*)d_in[5];
  const float* W_hh2 = (const float*)d_in[6];
  const float* b_ih2 = (const float*)d_in[7];
  const float* b_hh2 = (const float*)d_in[8];
  const float* mask1 = (const float*)d_in[9];
  const float* mask2 = (const float*)d_in[10];
  float* out = (float*)d_out;

  float* xg1 = (float*)d_ws;  // B*T*4H fp32 = 134,217,728 bytes

  xgemm<<<dim3(BB * TT / 256), dim3(256), 0, stream>>>(x, W_ih1, b_ih1, b_hh1, xg1);
  lstm2<<<dim3(BB), dim3(256), 131072, stream>>>(xg1, W_hh1, W_ih2, W_hh2,
                                                 b_ih2, b_hh2, mask1, mask2, out);
}